// Round 8
// baseline (337.182 us; speedup 1.0000x reference)
//
#include <hip/hip_runtime.h>
#include <hip/hip_bf16.h>

#define HIDDEN 64
#define NB 32
#define SCAN_BLOCK 1024
#define HSTR 72   // LDS row stride in shorts: %8==0 (16B align for b128)

typedef __attribute__((ext_vector_type(8))) short bf16x8;
typedef __attribute__((ext_vector_type(4))) float f32x4;

// ---- bf16 helpers ----
static __device__ __forceinline__ unsigned short f2bf(float x) {
    union { float f; unsigned u; } v; v.f = x;
    unsigned r = v.u + 0x7fffu + ((v.u >> 16) & 1u);
    return (unsigned short)(r >> 16);
}
static __device__ __forceinline__ float bf2f(unsigned short s) {
    union { unsigned u; float f; } v; v.u = ((unsigned)s) << 16;
    return v.f;
}
// packed pair: low 16 = a, high 16 = b (RNE, HW v_cvt_pk path)
static __device__ __forceinline__ unsigned pk2(float a, float b) {
    __hip_bfloat162 h = __float22bfloat162_rn(make_float2(a, b));
    unsigned u; __builtin_memcpy(&u, &h, 4); return u;
}
static __device__ __forceinline__ float fast_silu(float x) {
    float e = __expf(-x);
    return x * __builtin_amdgcn_rcpf(1.0f + e);
}

// ---------------------------------------------------------------------------
// Feature pack: feat[n][lane] = {scalar, v0, v1, v2} bf16 (8 B).
// ---------------------------------------------------------------------------
__global__ __launch_bounds__(256) void featpack_kernel(
    const float* __restrict__ scalar, const float* __restrict__ vector,
    ushort4* __restrict__ feat, int total)
{
    int i = blockIdx.x * 256 + threadIdx.x;
    if (i >= total) return;
    const int n = i >> 6, l = i & 63;
    const float* vp = vector + (size_t)n * 192 + l;
    ushort4 o;
    o.x = f2bf(scalar[i]);
    o.y = f2bf(vp[0]);
    o.z = f2bf(vp[64]);
    o.w = f2bf(vp[128]);
    feat[i] = o;
}

// ---------------------------------------------------------------------------
// CSR scan (3-pass multi-block) + scatter.
// ---------------------------------------------------------------------------
__global__ __launch_bounds__(SCAN_BLOCK) void scan_pass1(
    const int* __restrict__ counts, int* __restrict__ partial,
    int* __restrict__ blocksums, int N)
{
    __shared__ int tmp[SCAN_BLOCK];
    const int t = threadIdx.x;
    const int gid = blockIdx.x * SCAN_BLOCK + t;
    int v = (gid < N) ? counts[gid] : 0;
    tmp[t] = v;
    __syncthreads();
    for (int off = 1; off < SCAN_BLOCK; off <<= 1) {
        int x = (t >= off) ? tmp[t - off] : 0;
        __syncthreads();
        tmp[t] += x;
        __syncthreads();
    }
    if (gid < N) partial[gid] = tmp[t] - v;
    if (t == SCAN_BLOCK - 1) blocksums[blockIdx.x] = tmp[t];
}

__global__ __launch_bounds__(64) void scan_pass2(int* __restrict__ blocksums, int nb)
{
    const int t = threadIdx.x;
    int v = (t < nb) ? blocksums[t] : 0;
    int s = v;
    #pragma unroll
    for (int off = 1; off < 64; off <<= 1) {
        int x = __shfl_up(s, off, 64);
        if (t >= off) s += x;
    }
    if (t < nb) blocksums[t] = s - v;
}

__global__ __launch_bounds__(SCAN_BLOCK) void scan_pass3(
    const int* __restrict__ partial, const int* __restrict__ blocksums,
    int* __restrict__ offsets, int* __restrict__ cursors, int N, int E)
{
    const int gid = blockIdx.x * SCAN_BLOCK + threadIdx.x;
    if (gid < N) {
        int o = partial[gid] + blocksums[blockIdx.x];
        offsets[gid] = o;
        cursors[gid] = o;
    }
    if (blockIdx.x == 0 && threadIdx.x == 0) offsets[N] = E;
}

__global__ __launch_bounds__(256) void scatter_kernel(
    const int* __restrict__ edge_index, int* __restrict__ cursors,
    int2* __restrict__ pc, int E)
{
    int i = blockIdx.x * 256 + threadIdx.x;
    if (i < E) {
        int pos = atomicAdd(&cursors[edge_index[i]], 1);
        pc[pos] = make_int2(i, edge_index[E + i]);
    }
}

// ---------------------------------------------------------------------------
// Phase A (MFMA, edge order) + fused histogram. ONE MLP per wave:
// waves 0,1 -> scalar MLP, waves 2,3 -> vector MLP (halves VGPR/wave).
//
// Layer 1 computed transposed: D1[hidden][edge] = W1^T(A) @ EL^T(B).
// Its C-layout (col=edge l16, row=hidden q*4+r) feeds layer 2 DIRECTLY as a
// B-fragment under the k-permutation hidden(q,kk,j)=16*(2kk+(j>>2))+4q+(j&3),
// with W2^T's A-fragment preloaded in the SAME permuted k order (MFMA sums
// over k, so any consistent k-permutation of A and B is exact).
// -> no inter-layer LDS round trip. Only the final store stages through LDS.
// ---------------------------------------------------------------------------
__global__ __launch_bounds__(256) void mlp_mfma_kernel(
    const float* __restrict__ edge_length,   // [E,32]
    const int*   __restrict__ edge_index,    // [2,E] (rows for hist)
    int* __restrict__ counts,                // [N] (pre-zeroed)
    const float* __restrict__ sw1, const float* __restrict__ sb1,
    const float* __restrict__ sw2, const float* __restrict__ sb2,
    const float* __restrict__ vw1, const float* __restrict__ vb1,
    const float* __restrict__ vw2, const float* __restrict__ vb2,
    unsigned short* __restrict__ W,          // [E,128] bf16
    int E, int nchunks)
{
    __shared__ short Hs[4][64 * HSTR];       // per-wave store staging (9216 B)

    const int t    = threadIdx.x;
    const int lane = t & 63;
    const int wid  = t >> 6;                 // 0..3
    const int slot = wid & 1;                // chunk slot within block
    const int m    = wid >> 1;               // 0 = scalar MLP, 1 = vector MLP
    const int quad = lane >> 4;
    const int l16  = lane & 15;
    short* Hw = Hs[wid];

    const float* w1 = m ? vw1 : sw1;
    const float* b1 = m ? vb1 : sb1;
    const float* w2 = m ? vw2 : sw2;
    const float* b2 = m ? vb2 : sb2;

    // ---- preamble: this wave's MLP weights in registers ----
    bf16x8 w1a[4];          // A-frag of W1^T: a[j] = W1[q*8+j][mt*16+l16]
    bf16x8 a2f[2][4];       // A-frag of W2^T, k-permuted:
                            //   a[j] = W2[16*(2kk+(j>>2))+4q+(j&3)][mt*16+l16]
    float4 b1f[4], b2f[4];  // bias rows mt*16+q*4 .. +3
    #pragma unroll
    for (int mt = 0; mt < 4; ++mt) {
        const int col = mt * 16 + l16;
        #pragma unroll
        for (int j = 0; j < 8; ++j)
            w1a[mt][j] = (short)f2bf(w1[(quad * 8 + j) * HIDDEN + col]);
        #pragma unroll
        for (int kk = 0; kk < 2; ++kk)
            #pragma unroll
            for (int j = 0; j < 8; ++j) {
                const int h = 16 * (2 * kk + (j >> 2)) + 4 * quad + (j & 3);
                a2f[kk][mt][j] = (short)f2bf(w2[h * HIDDEN + col]);
            }
        b1f[mt] = *(const float4*)(b1 + mt * 16 + quad * 4);
        b2f[mt] = *(const float4*)(b2 + mt * 16 + quad * 4);
    }

    const int stride = gridDim.x * 2;

    for (int c = blockIdx.x * 2 + slot; c < nchunks; c += stride) {
        const int j0 = c * 64;

        // fused histogram (once per chunk: only the m=0 wave)
        if (m == 0) {
            const int e = j0 + lane;
            if (e < E) atomicAdd(&counts[edge_index[e]], 1);
        }

        // ---- EL^T B-frags: lane l16 = edge, quad = basis group ----
        bf16x8 af[4];
        #pragma unroll
        for (int nt = 0; nt < 4; ++nt) {
            int e = j0 + nt * 16 + l16;
            if (e >= E) e = E - 1;
            const float* r = edge_length + (size_t)e * NB + quad * 8;
            float4 u0 = *(const float4*)r;
            float4 u1 = *(const float4*)(r + 4);
            union { bf16x8 v; unsigned u[4]; } p;
            p.u[0] = pk2(u0.x, u0.y); p.u[1] = pk2(u0.z, u0.w);
            p.u[2] = pk2(u1.x, u1.y); p.u[3] = pk2(u1.z, u1.w);
            af[nt] = p.v;
        }

        #pragma unroll
        for (int nt = 0; nt < 4; ++nt) {
            // ---- layer 1 (transposed) + SiLU, all in registers ----
            float h[4][4];                       // [mt=hidden tile][r4]
            #pragma unroll
            for (int mt = 0; mt < 4; ++mt) {
                f32x4 cf = {b1f[mt].x, b1f[mt].y, b1f[mt].z, b1f[mt].w};
                cf = __builtin_amdgcn_mfma_f32_16x16x32_bf16(w1a[mt], af[nt], cf, 0, 0, 0);
                #pragma unroll
                for (int r4 = 0; r4 < 4; ++r4)
                    h[mt][r4] = fast_silu(cf[r4]);
            }

            // ---- repack H as layer-2 B-frags (k-permuted, in-register) ----
            union { bf16x8 v; unsigned u[4]; } bf0, bf1;
            bf0.u[0] = pk2(h[0][0], h[0][1]); bf0.u[1] = pk2(h[0][2], h[0][3]);
            bf0.u[2] = pk2(h[1][0], h[1][1]); bf0.u[3] = pk2(h[1][2], h[1][3]);
            bf1.u[0] = pk2(h[2][0], h[2][1]); bf1.u[1] = pk2(h[2][2], h[2][3]);
            bf1.u[2] = pk2(h[3][0], h[3][1]); bf1.u[3] = pk2(h[3][2], h[3][3]);

            // ---- layer 2: D2[o][edge]; stage to LDS for coalesced store ----
            #pragma unroll
            for (int mt = 0; mt < 4; ++mt) {
                f32x4 cf = {b2f[mt].x, b2f[mt].y, b2f[mt].z, b2f[mt].w};
                cf = __builtin_amdgcn_mfma_f32_16x16x32_bf16(a2f[0][mt], bf0.v, cf, 0, 0, 0);
                cf = __builtin_amdgcn_mfma_f32_16x16x32_bf16(a2f[1][mt], bf1.v, cf, 0, 0, 0);
                const unsigned u0 = pk2(cf[0], cf[1]);
                const unsigned u1 = pk2(cf[2], cf[3]);
                // LDS layout [edge][o]: rows o = mt*16+quad*4 .. +3 contiguous
                *(uint2*)(Hw + (nt * 16 + l16) * HSTR + mt * 16 + quad * 4) =
                    make_uint2(u0, u1);
            }
        }

        // ---- store stage: LDS -> global, 16 B/lane (per-wave, no barrier) ----
        #pragma unroll
        for (int i = 0; i < 8; ++i) {
            const int row = i * 8 + (lane >> 3);
            bf16x8 v = *(const bf16x8*)(Hw + row * HSTR + (lane & 7) * 8);
            if (j0 + row < E)
                *(bf16x8*)(W + (size_t)(j0 + row) * 128 + m * 64 + (lane & 7) * 8) = v;
        }
    }
}

// ---------------------------------------------------------------------------
// Phase B: one wave per node; 1-deep pipeline; bf16 packed features.
// ---------------------------------------------------------------------------
__global__ __launch_bounds__(256) void node_kernel_feat(
    const ushort4* __restrict__ feat,       // [N*64] bf16 {s,v0,v1,v2}
    const int* __restrict__ offsets,        // [N+1]
    const int2* __restrict__ pc,            // [E] {e, col}
    const unsigned short* __restrict__ W,   // [E,128] bf16
    float* __restrict__ out_scalar,
    float* __restrict__ out_vector,
    int N)
{
    const int lane = threadIdx.x & 63;
    const int wave = blockIdx.x * 4 + (threadIdx.x >> 6);
    const int nw   = gridDim.x * 4;

    for (int n = wave; n < N; n += nw) {
        const int beg = offsets[n];
        const int end = offsets[n + 1];

        float as = 0.0f, a0 = 0.0f, a1 = 0.0f, a2 = 0.0f;
        float ws = 0, wv = 0, s = 0, v0 = 0, v1 = 0, v2 = 0;

        if (beg < end) {
            const int2 p = pc[beg];
            const unsigned short* wp = W + (size_t)p.x * 128;
            ws = bf2f(wp[lane]); wv = bf2f(wp[64 + lane]);
            const ushort4 f = feat[(size_t)p.y * 64 + lane];
            s = bf2f(f.x); v0 = bf2f(f.y); v1 = bf2f(f.z); v2 = bf2f(f.w);
        }

        for (int j = beg; j < end; ++j) {
            const int jn = (j + 1 < end) ? j + 1 : j;
            const int2 p = pc[jn];
            const unsigned short* wp = W + (size_t)p.x * 128;
            const float wsn = bf2f(wp[lane]);
            const float wvn = bf2f(wp[64 + lane]);
            const ushort4 f = feat[(size_t)p.y * 64 + lane];
            const float sn  = bf2f(f.x);
            const float v0n = bf2f(f.y);
            const float v1n = bf2f(f.z);
            const float v2n = bf2f(f.w);

            as = fmaf(s,  ws, as);
            a0 = fmaf(v0, wv, a0);
            a1 = fmaf(v1, wv, a1);
            a2 = fmaf(v2, wv, a2);

            ws = wsn; wv = wvn; s = sn; v0 = v0n; v1 = v1n; v2 = v2n;
        }

        out_scalar[(size_t)n * HIDDEN + lane] = as;
        float* ov = out_vector + (size_t)n * 3 * HIDDEN;
        ov[lane]       = a0;
        ov[64 + lane]  = a1;
        ov[128 + lane] = a2;
    }
}

// Fallback if workspace can't hold the feat table.
__global__ __launch_bounds__(256) void node_kernel_f32(
    const float* __restrict__ scalar,
    const float* __restrict__ vector,
    const int* __restrict__ offsets,
    const int2* __restrict__ pc,
    const unsigned short* __restrict__ W,
    float* __restrict__ out_scalar,
    float* __restrict__ out_vector,
    int N)
{
    const int lane = threadIdx.x & 63;
    const int wave = blockIdx.x * 4 + (threadIdx.x >> 6);
    const int nw   = gridDim.x * 4;

    for (int n = wave; n < N; n += nw) {
        const int beg = offsets[n];
        const int end = offsets[n + 1];
        float as = 0.0f, a0 = 0.0f, a1 = 0.0f, a2 = 0.0f;
        for (int j = beg; j < end; ++j) {
            const int2 p = pc[j];
            const unsigned short* wp = W + (size_t)p.x * 128;
            const float w_s = bf2f(wp[lane]);
            const float w_v = bf2f(wp[64 + lane]);
            const float* sp = scalar + (size_t)p.y * HIDDEN;
            const float* vp = vector + (size_t)p.y * 3 * HIDDEN;
            as = fmaf(sp[lane],       w_s, as);
            a0 = fmaf(vp[lane],       w_v, a0);
            a1 = fmaf(vp[64 + lane],  w_v, a1);
            a2 = fmaf(vp[128 + lane], w_v, a2);
        }
        out_scalar[(size_t)n * HIDDEN + lane] = as;
        float* ov = out_vector + (size_t)n * 3 * HIDDEN;
        ov[lane]       = a0;
        ov[64 + lane]  = a1;
        ov[128 + lane] = a2;
    }
}

extern "C" void kernel_launch(void* const* d_in, const int* in_sizes, int n_in,
                              void* d_out, int out_size, void* d_ws, size_t ws_size,
                              hipStream_t stream) {
    const float* scalar      = (const float*)d_in[0];
    const float* vector      = (const float*)d_in[1];
    // d_in[2] = edge_sh (unused by reference)
    const float* edge_length = (const float*)d_in[3];
    const int*   edge_index  = (const int*)d_in[4];
    const float* sw1 = (const float*)d_in[5];
    const float* sb1 = (const float*)d_in[6];
    const float* sw2 = (const float*)d_in[7];
    const float* sb2 = (const float*)d_in[8];
    const float* vw1 = (const float*)d_in[9];
    const float* vb1 = (const float*)d_in[10];
    const float* vw2 = (const float*)d_in[11];
    const float* vb2 = (const float*)d_in[12];

    const int N = in_sizes[0] / HIDDEN;       // 50000
    const int E = in_sizes[4] / 2;            // 500000

    float* out_scalar = (float*)d_out;
    float* out_vector = (float*)d_out + (size_t)N * HIDDEN;

    // ---- workspace layout ----
    size_t off = 0;
    unsigned short* W = (unsigned short*)d_ws;           // [E,128] bf16 = 128 MB
    off += (size_t)E * 128 * 2;
    int2* pc = (int2*)((char*)d_ws + off);               // [E] = 4 MB
    off += (size_t)E * 8;
    int* ib = (int*)((char*)d_ws + off);
    int* counts    = ib;                                  // [N]
    int* partial   = ib + N;                              // [N]
    int* offsets   = ib + 2 * N;                          // [N+1]
    int* cursors   = ib + 3 * N + 1;                      // [N]
    int* blocksums = ib + 4 * N + 1;                      // [64]
    off += ((size_t)4 * N + 1 + 64) * 4;
    off = (off + 15) & ~(size_t)15;
    ushort4* feat = (ushort4*)((char*)d_ws + off);        // [N*64] = 25.6 MB
    const bool use_feat = (off + (size_t)N * 64 * 8) <= ws_size;

    hipMemsetAsync(counts, 0, (size_t)N * sizeof(int), stream);

    const int egrid = (E + 255) / 256;

    if (use_feat) {
        const int total = N * 64;
        featpack_kernel<<<(total + 255) / 256, 256, 0, stream>>>(
            scalar, vector, feat, total);
    }

    // Phase A (+ fused histogram): 2 chunk-slots per block (waves split by MLP)
    const int nchunks = (E + 63) / 64;                    // 7813
    const int agrid   = (nchunks + 1) / 2;                // 3907 blocks
    mlp_mfma_kernel<<<agrid, 256, 0, stream>>>(
        edge_length, edge_index, counts,
        sw1, sb1, sw2, sb2, vw1, vb1, vw2, vb2,
        W, E, nchunks);

    // CSR scan + scatter
    const int nb = (N + SCAN_BLOCK - 1) / SCAN_BLOCK;
    scan_pass1<<<nb, SCAN_BLOCK, 0, stream>>>(counts, partial, blocksums, N);
    scan_pass2<<<1, 64, 0, stream>>>(blocksums, nb);
    scan_pass3<<<nb, SCAN_BLOCK, 0, stream>>>(partial, blocksums, offsets, cursors, N, E);
    scatter_kernel<<<egrid, 256, 0, stream>>>(edge_index, cursors, pc, E);

    // Phase B
    const int ngrid = (N + 3) / 4;
    if (use_feat) {
        node_kernel_feat<<<ngrid, 256, 0, stream>>>(
            feat, offsets, pc, W, out_scalar, out_vector, N);
    } else {
        node_kernel_f32<<<ngrid, 256, 0, stream>>>(
            scalar, vector, offsets, pc, W, out_scalar, out_vector, N);
    }
}